// Round 4
// baseline (424.676 us; speedup 1.0000x reference)
//
#include <hip/hip_runtime.h>
#include <hip/hip_bf16.h>
#include <math.h>

typedef unsigned short u16;
typedef float float4e __attribute__((ext_vector_type(4)));
typedef short short8 __attribute__((ext_vector_type(8)));
typedef unsigned short ushort8 __attribute__((ext_vector_type(8)));
typedef unsigned short u16x4 __attribute__((ext_vector_type(4)));

#define SEQ 2048
#define DIM 512
#define NB  4

__device__ __forceinline__ float bf2f(u16 h) {
    return __uint_as_float(((unsigned)h) << 16);
}
__device__ __forceinline__ u16 f2bf(float f) {
    __hip_bfloat16 h = __float2bfloat16(f);
    return *reinterpret_cast<u16*>(&h);
}
__device__ __forceinline__ float curv_of(float raw) {
    return -2.0f + 2.0f * (tanhf(raw) + 1.0f);   // bounds (-2,2)
}

// ---------------- fused conversions + lsum zero (vectorized x4) ----------------
__global__ __launch_bounds__(256) void cvt_all_kernel(
    const float* __restrict__ x, const float* __restrict__ Wq,
    const float* __restrict__ Wk, const float* __restrict__ Wv,
    u16* __restrict__ x_bf, u16* __restrict__ Wcat, float* __restrict__ lsum)
{
    const int n_x = NB * SEQ * DIM, n_w = DIM * DIM;
    int gid = blockIdx.x * 256 + threadIdx.x;
    if (gid < NB * SEQ) lsum[gid] = 0.f;
    int i4 = gid * 4;
    if (i4 < n_x) {
        float4 v = *(const float4*)&x[i4];
        u16x4 h = {f2bf(v.x), f2bf(v.y), f2bf(v.z), f2bf(v.w)};
        *(u16x4*)&x_bf[i4] = h;
    } else if (i4 < n_x + 3 * n_w) {
        int j = i4 - n_x;
        const float* W = (j < n_w) ? Wq : (j < 2 * n_w ? Wk : Wv);
        int off = j % n_w;
        float4 v = *(const float4*)&W[off];
        u16x4 h = {f2bf(v.x), f2bf(v.y), f2bf(v.z), f2bf(v.w)};
        *(u16x4*)&Wcat[j] = h;
    }
}

// =====================================================================
// Barrier-free, LDS-free wave GEMM: each wave owns a 64x32 output tile,
// loads MFMA fragments DIRECTLY from global (row-major [.,K] operands),
// fragment addr = row*ld + k0 + kk*32 + quad*8 (16B aligned). No wave
// coupling -> pure TLP latency hiding; compiler pipelines the unrolled
// K loop with counted vmcnt. acc[4][2] fp32x4 = 32 VGPR.
//
// QKV: M=8192, N=1536, K=512. Block = 128x64 (4 waves). +bias, vT emit.
// =====================================================================
__global__ __launch_bounds__(256, 4) void gemm_qkv_kernel(
    const u16* __restrict__ A, const u16* __restrict__ Bt,
    u16* __restrict__ C, u16* __restrict__ vT,
    const float* __restrict__ bq, const float* __restrict__ bk, const float* __restrict__ bv)
{
    const int lda = 512, ldb = 512, ldc = 1536;
    int bn = blockIdx.x, bm = blockIdx.y;

    int t = threadIdx.x, wave = t >> 6, lane = t & 63;
    int wr = wave >> 1, wc = wave & 1;
    int lrow = lane & 15, quad = lane >> 4;

    const u16* Aw = A + (size_t)(bm * 128 + wr * 64) * lda;
    const u16* Bw = Bt + (size_t)(bn * 64 + wc * 32) * ldb;

    float4e acc[4][2];
#pragma unroll
    for (int i = 0; i < 4; i++)
#pragma unroll
        for (int j = 0; j < 2; j++) acc[i][j] = (float4e){0.f, 0.f, 0.f, 0.f};

#pragma unroll
    for (int kt = 0; kt < 8; ++kt) {
        int k0 = kt * 64;
        short8 af[4][2], bfr[2][2];
#pragma unroll
        for (int im = 0; im < 4; im++)
#pragma unroll
            for (int kk = 0; kk < 2; kk++)
                af[im][kk] = *(const short8*)&Aw[(size_t)(im * 16 + lrow) * lda + k0 + kk * 32 + quad * 8];
#pragma unroll
        for (int in = 0; in < 2; in++)
#pragma unroll
            for (int kk = 0; kk < 2; kk++)
                bfr[in][kk] = *(const short8*)&Bw[(size_t)(in * 16 + lrow) * ldb + k0 + kk * 32 + quad * 8];
#pragma unroll
        for (int kk = 0; kk < 2; kk++)
#pragma unroll
            for (int im = 0; im < 4; im++)
#pragma unroll
                for (int in = 0; in < 2; in++)
                    acc[im][in] = __builtin_amdgcn_mfma_f32_16x16x32_bf16(af[im][kk], bfr[in][kk], acc[im][in], 0, 0, 0);
    }

#pragma unroll
    for (int in = 0; in < 2; in++) {
        int gj = bn * 64 + wc * 32 + in * 16 + lrow;
        float bias = (gj < 512) ? bq[gj] : (gj < 1024 ? bk[gj - 512] : bv[gj - 1024]);
#pragma unroll
        for (int im = 0; im < 4; im++) {
            int gi0 = bm * 128 + wr * 64 + im * 16 + quad * 4;
            u16x4 pack;
#pragma unroll
            for (int r = 0; r < 4; r++) {
                u16 hv = f2bf(acc[im][in][r] + bias);
                C[(size_t)(gi0 + r) * ldc + gj] = hv;
                pack[r] = hv;
            }
            if (gj >= 1024) {   // vT[b][d][s], 4 consecutive s -> 8B store
                int bb = gi0 >> 11, s = gi0 & 2047;
                *(u16x4*)&vT[((size_t)bb * DIM + (gj - 1024)) * SEQ + s] = pack;
            }
        }
    }
}

// =====================================================================
// Scores: barrier-free wave GEMM, M=N=2048 per batch, K=512, causal.
// Block = 128x64 (4 waves of 64x32). Epilogue: curvature dist + exp2
// (unnormalized bf16) + lsum atomics.
// =====================================================================
__global__ __launch_bounds__(256, 4) void gemm_scores_kernel(
    const u16* __restrict__ qm, const u16* __restrict__ km,
    u16* __restrict__ attnH,
    float* __restrict__ lsum,
    const float* __restrict__ qn2v, const float* __restrict__ kn2v,
    const float* __restrict__ curvp, const float* __restrict__ tempp)
{
    const int lda = 512, ldb = 512, ldc = SEQ;
    int bn = blockIdx.x, bm = blockIdx.y, b = blockIdx.z;
    if (bn > 2 * bm + 1) return;   // fully-masked tile

    int t = threadIdx.x, wave = t >> 6, lane = t & 63;
    int wr = wave >> 1, wc = wave & 1;
    int lrow = lane & 15, quad = lane >> 4;

    const u16* Aw = qm + (size_t)b * SEQ * DIM + (size_t)(bm * 128 + wr * 64) * lda;
    const u16* Bw = km + (size_t)b * SEQ * DIM + (size_t)(bn * 64 + wc * 32) * ldb;

    float4e acc[4][2];
#pragma unroll
    for (int i = 0; i < 4; i++)
#pragma unroll
        for (int j = 0; j < 2; j++) acc[i][j] = (float4e){0.f, 0.f, 0.f, 0.f};

#pragma unroll
    for (int kt = 0; kt < 8; ++kt) {
        int k0 = kt * 64;
        short8 af[4][2], bfr[2][2];
#pragma unroll
        for (int im = 0; im < 4; im++)
#pragma unroll
            for (int kk = 0; kk < 2; kk++)
                af[im][kk] = *(const short8*)&Aw[(size_t)(im * 16 + lrow) * lda + k0 + kk * 32 + quad * 8];
#pragma unroll
        for (int in = 0; in < 2; in++)
#pragma unroll
            for (int kk = 0; kk < 2; kk++)
                bfr[in][kk] = *(const short8*)&Bw[(size_t)(in * 16 + lrow) * ldb + k0 + kk * 32 + quad * 8];
#pragma unroll
        for (int kk = 0; kk < 2; kk++)
#pragma unroll
            for (int im = 0; im < 4; im++)
#pragma unroll
                for (int in = 0; in < 2; in++)
                    acc[im][in] = __builtin_amdgcn_mfma_f32_16x16x32_bf16(af[im][kk], bfr[in][kk], acc[im][in], 0, 0, 0);
    }

    float kv = curv_of(curvp[0]);
    float absk = fabsf(kv);
    float sk = sqrtf(fmaxf(absk, 1e-5f));
    float invT = 1.0f / (tempp[0] + 1e-8f);
    float Cexp = -1.4426950408889634f * invT;   // e = exp2(dist * Cexp)
    u16* Cb = attnH + (size_t)b * SEQ * SEQ;

    float psum[4][4];
#pragma unroll
    for (int im = 0; im < 4; im++)
#pragma unroll
        for (int r = 0; r < 4; r++) psum[im][r] = 0.f;

    float kn[2];
#pragma unroll
    for (int in = 0; in < 2; in++)
        kn[in] = kn2v[b * SEQ + bn * 64 + wc * 32 + in * 16 + lrow];

#pragma unroll
    for (int im = 0; im < 4; im++) {
#pragma unroll
        for (int r = 0; r < 4; r++) {
            int gi = bm * 128 + wr * 64 + im * 16 + quad * 4 + r;
            float qn = qn2v[b * SEQ + gi];
#pragma unroll
            for (int in = 0; in < 2; in++) {
                int gj = bn * 64 + wc * 32 + in * 16 + lrow;
                float dot = acc[im][in][r];
                float diff2 = fmaxf(qn + kn[in] - 2.f * dot, 0.f);
                float dist;
                if (absk < 0.01f) {
                    dist = sqrtf(diff2 + 1e-12f);
                } else if (kv < 0.f) {
                    float denom = fmaxf((1.f - absk * qn) * (1.f - absk * kn[in]), 1e-5f);
                    float arg = fmaxf(1.f + 2.f * absk * diff2 / denom, 1.f + 1e-7f);
                    dist = acoshf(arg) / sk;
                } else {
                    float c = fminf(fmaxf(absk * dot, -1.f + 1e-7f), 1.f - 1e-7f);
                    dist = acosf(c) / sk;
                }
                float e = (gj <= gi) ? exp2f(dist * Cexp) : 0.f;   // scores<=0 -> no max shift
                Cb[(size_t)gi * ldc + gj] = f2bf(e);
                psum[im][r] += e;
            }
        }
    }
#pragma unroll
    for (int im = 0; im < 4; im++)
#pragma unroll
        for (int r = 0; r < 4; r++) {
            float v = psum[im][r];
            v += __shfl_xor(v, 1);
            v += __shfl_xor(v, 2);
            v += __shfl_xor(v, 4);
            v += __shfl_xor(v, 8);
            if (lrow == 0) {
                int gi = bm * 128 + wr * 64 + im * 16 + quad * 4 + r;
                atomicAdd(&lsum[b * SEQ + gi], v);
            }
        }
}

// =====================================================================
// PV: barrier-free wave GEMM. M=2048, N=512, K causal ((2bm+2) ktiles
// for the 128-row block). A=attnH [S][S] bf16, B=vT [D][S] bf16.
// Direct fp32 store with 1/lsum.
// =====================================================================
__global__ __launch_bounds__(256, 4) void gemm_pv_kernel(
    const u16* __restrict__ attnH, const u16* __restrict__ vT,
    float* __restrict__ out, const float* __restrict__ lsum)
{
    const int lda = SEQ, ldb = SEQ, ldc = DIM;
    int bn = blockIdx.x, bm = blockIdx.y, b = blockIdx.z;

    int t = threadIdx.x, wave = t >> 6, lane = t & 63;
    int wr = wave >> 1, wc = wave & 1;
    int lrow = lane & 15, quad = lane >> 4;

    const u16* Aw = attnH + (size_t)b * SEQ * SEQ + (size_t)(bm * 128 + wr * 64) * lda;
    const u16* Bw = vT + (size_t)b * DIM * SEQ + (size_t)(bn * 64 + wc * 32) * ldb;

    float4e acc[4][2];
#pragma unroll
    for (int i = 0; i < 4; i++)
#pragma unroll
        for (int j = 0; j < 2; j++) acc[i][j] = (float4e){0.f, 0.f, 0.f, 0.f};

    int ktEnd = 2 * bm + 2;   // causal: cols <= bm*128+127
#pragma unroll 2
    for (int kt = 0; kt < ktEnd; ++kt) {
        int k0 = kt * 64;
        short8 af[4][2], bfr[2][2];
#pragma unroll
        for (int im = 0; im < 4; im++)
#pragma unroll
            for (int kk = 0; kk < 2; kk++)
                af[im][kk] = *(const short8*)&Aw[(size_t)(im * 16 + lrow) * lda + k0 + kk * 32 + quad * 8];
#pragma unroll
        for (int in = 0; in < 2; in++)
#pragma unroll
            for (int kk = 0; kk < 2; kk++)
                bfr[in][kk] = *(const short8*)&Bw[(size_t)(in * 16 + lrow) * ldb + k0 + kk * 32 + quad * 8];
#pragma unroll
        for (int kk = 0; kk < 2; kk++)
#pragma unroll
            for (int im = 0; im < 4; im++)
#pragma unroll
                for (int in = 0; in < 2; in++)
                    acc[im][in] = __builtin_amdgcn_mfma_f32_16x16x32_bf16(af[im][kk], bfr[in][kk], acc[im][in], 0, 0, 0);
    }

    float* Cb = out + (size_t)b * SEQ * DIM;
#pragma unroll
    for (int im = 0; im < 4; im++)
#pragma unroll
        for (int r = 0; r < 4; r++) {
            int gi = bm * 128 + wr * 64 + im * 16 + quad * 4 + r;
            float invl = 1.0f / lsum[b * SEQ + gi];
#pragma unroll
            for (int in = 0; in < 2; in++) {
                int gd = bn * 64 + wc * 32 + in * 16 + lrow;
                Cb[(size_t)gi * ldc + gd] = acc[im][in][r] * invl;
            }
        }
}

// ---------------- projection: wave-per-row, 16B vector loads/stores ----------------
__global__ __launch_bounds__(256) void project_kernel(
    const u16* __restrict__ qkvh,
    u16* __restrict__ qm, u16* __restrict__ km,
    float* __restrict__ qn2, float* __restrict__ kn2,
    const float* __restrict__ curvp)
{
    int wave = threadIdx.x >> 6, lane = threadIdx.x & 63;
    int r = blockIdx.x * 4 + wave;
    float kv = curv_of(curvp[0]);
    float absk = fabsf(kv);
    float sk = sqrtf(fmaxf(absk, 1e-5f));

    const u16* qrow = qkvh + (size_t)r * 1536;
    ushort8 qh = *(const ushort8*)&qrow[lane * 8];
    ushort8 kh = *(const ushort8*)&qrow[512 + lane * 8];

    float qv[8], kw[8];
    float sq = 0.f, s2 = 0.f;
#pragma unroll
    for (int e = 0; e < 8; e++) {
        qv[e] = bf2f(qh[e]); sq += qv[e] * qv[e];
        kw[e] = bf2f(kh[e]); s2 += kw[e] * kw[e];
    }
#pragma unroll
    for (int off = 1; off < 64; off <<= 1) {
        sq += __shfl_xor(sq, off);
        s2 += __shfl_xor(s2, off);
    }

    float sclq, sclk;
    {
        float nq = sqrtf(sq + 1e-12f);
        float nk = sqrtf(s2 + 1e-12f);
        if (absk < 0.01f) { sclq = 1.f; sclk = 1.f; }
        else if (kv < 0.f) {
            float mx = (1.0f - 1e-3f) / sk;
            sclq = fminf(1.f, mx / nq);
            sclk = fminf(1.f, mx / nk);
        } else {
            sclq = 1.f / (nq * sk);
            sclk = 1.f / (nk * sk);
        }
    }
    if (lane == 0) {
        qn2[r] = sq * sclq * sclq;
        kn2[r] = s2 * sclk * sclk;
    }
    ushort8 qo, ko;
#pragma unroll
    for (int e = 0; e < 8; e++) {
        qo[e] = f2bf(qv[e] * sclq);
        ko[e] = f2bf(kw[e] * sclk);
    }
    *(ushort8*)&qm[(size_t)r * 512 + lane * 8] = qo;
    *(ushort8*)&km[(size_t)r * 512 + lane * 8] = ko;
}

// ---------------- normalize: attnH bf16 -> attnF fp32 (zero upper-tri) ----------------
__global__ __launch_bounds__(256) void norm_attn_kernel(
    const u16* __restrict__ attnH, const float* __restrict__ lsum,
    float* __restrict__ attnF)
{
    int i = blockIdx.x, b = blockIdx.y, t = threadIdx.x;
    float inv = 1.0f / lsum[b * SEQ + i];
    const u16* rowh = attnH + ((size_t)b * SEQ + i) * SEQ;
    float* row = attnF + ((size_t)b * SEQ + i) * SEQ;
    int L = i + 1;
    int j0 = t * 8;
    float4 lo, hi;
    if (j0 + 8 <= L) {
        ushort8 h = *(const ushort8*)&rowh[j0];
        lo.x = bf2f(h[0]) * inv; lo.y = bf2f(h[1]) * inv;
        lo.z = bf2f(h[2]) * inv; lo.w = bf2f(h[3]) * inv;
        hi.x = bf2f(h[4]) * inv; hi.y = bf2f(h[5]) * inv;
        hi.z = bf2f(h[6]) * inv; hi.w = bf2f(h[7]) * inv;
    } else {
        float v[8];
#pragma unroll
        for (int e = 0; e < 8; e++)
            v[e] = (j0 + e < L) ? bf2f(rowh[j0 + e]) * inv : 0.f;
        lo = (float4){v[0], v[1], v[2], v[3]};
        hi = (float4){v[4], v[5], v[6], v[7]};
    }
    *(float4*)&row[j0] = lo;
    *(float4*)&row[j0 + 4] = hi;
}

// ---------------- launch ----------------
extern "C" void kernel_launch(void* const* d_in, const int* in_sizes, int n_in,
                              void* d_out, int out_size, void* d_ws, size_t ws_size,
                              hipStream_t stream) {
    (void)in_sizes; (void)n_in; (void)out_size; (void)ws_size;

    const float* x    = (const float*)d_in[0];
    const float* Wq   = (const float*)d_in[1];
    const float* bq   = (const float*)d_in[2];
    const float* Wk   = (const float*)d_in[3];
    const float* bk   = (const float*)d_in[4];
    const float* Wv   = (const float*)d_in[5];
    const float* bv   = (const float*)d_in[6];
    const float* curv = (const float*)d_in[7];
    const float* temp = (const float*)d_in[8];

    float* out   = (float*)d_out;                       // [4][2048][512]
    float* attnF = out + (size_t)NB * SEQ * DIM;        // [4][2048][2048]

    char* ws = (char*)d_ws;
    // layout (bytes):
    //   0        x_bf    8,388,608   (dead after QKV)
    //   8388608  Wcat    1,572,864   (dead after QKV)
    //   9961472  qkvh   25,165,824   (dead after project)
    //   35127296 qm      8,388,608
    //   43515904 km      8,388,608
    //   51904512 vT      8,388,608   (written by QKV epilogue)
    //   60293120 qn2        32,768
    //   60325888 kn2        32,768
    //   60358656 lsum       32,768
    // attnH (33,554,432) aliases [0, 33554432) — x_bf/Wcat/qkvh all dead by then.
    u16*   x_bf  = (u16*)(ws + 0);
    u16*   Wcat  = (u16*)(ws + 8388608);
    u16*   qkvh  = (u16*)(ws + 9961472);
    u16*   qm    = (u16*)(ws + 35127296);
    u16*   km    = (u16*)(ws + 43515904);
    u16*   vT    = (u16*)(ws + 51904512);
    float* qn2   = (float*)(ws + 60293120);
    float* kn2   = (float*)(ws + 60325888);
    float* lsum  = (float*)(ws + 60358656);
    u16*   attnH = (u16*)(ws + 0);

    // K0: conversions + lsum zero
    {
        int n_tot = (NB * SEQ * DIM + 3 * DIM * DIM) / 4;
        cvt_all_kernel<<<(n_tot + 255) / 256, 256, 0, stream>>>(x, Wq, Wk, Wv, x_bf, Wcat, lsum);
    }

    // K1: QKV GEMM (M=8192, N=1536, K=512) + bias + fused V-transpose
    gemm_qkv_kernel<<<dim3(1536 / 64, 8192 / 128, 1), 256, 0, stream>>>(
        x_bf, Wcat, qkvh, vT, bq, bk, bv);

    // K2: projection
    project_kernel<<<NB * SEQ / 4, 256, 0, stream>>>(qkvh, qm, km, qn2, kn2, curv);

    // K3: scores + dist + exp (unnormalized bf16) + row sums
    gemm_scores_kernel<<<dim3(SEQ / 64, SEQ / 128, NB), 256, 0, stream>>>(
        qm, km, attnH, lsum, qn2, kn2, curv, temp);

    // K4: PV full causal K per block, direct store with 1/l
    gemm_pv_kernel<<<dim3(DIM / 64, SEQ / 128, NB), 256, 0, stream>>>(
        attnH, vT, out, lsum);

    // K5: attention fp32 output from bf16 + 1/l
    norm_attn_kernel<<<dim3(SEQ, NB), 256, 0, stream>>>(attnH, lsum, attnF);
}

// Round 5
// 275.953 us; speedup vs baseline: 1.5389x; 1.5389x over previous
//
#include <hip/hip_runtime.h>
#include <hip/hip_bf16.h>
#include <math.h>

typedef unsigned short u16;
typedef float float4e __attribute__((ext_vector_type(4)));
typedef short short8 __attribute__((ext_vector_type(8)));
typedef unsigned short ushort8 __attribute__((ext_vector_type(8)));
typedef unsigned short u16x4 __attribute__((ext_vector_type(4)));

#define SEQ 2048
#define DIM 512
#define NB  4

__device__ __forceinline__ float bf2f(u16 h) {
    return __uint_as_float(((unsigned)h) << 16);
}
__device__ __forceinline__ u16 f2bf(float f) {
    __hip_bfloat16 h = __float2bfloat16(f);
    return *reinterpret_cast<u16*>(&h);
}
__device__ __forceinline__ float curv_of(float raw) {
    return -2.0f + 2.0f * (tanhf(raw) + 1.0f);   // bounds (-2,2)
}
// async global->LDS, 16B per lane; lds base wave-uniform (lane lands at base+lane*16)
__device__ __forceinline__ void gl_lds16(const u16* g, u16* lds) {
    __builtin_amdgcn_global_load_lds(
        (const __attribute__((address_space(1))) unsigned int*)g,
        (__attribute__((address_space(3))) unsigned int*)lds, 16, 0, 0);
}

// ---------------- fused conversions + zero lsum/qn2r/kn2r ----------------
__global__ __launch_bounds__(256) void cvt_all_kernel(
    const float* __restrict__ x, const float* __restrict__ Wq,
    const float* __restrict__ Wk, const float* __restrict__ Wv,
    u16* __restrict__ x_bf, u16* __restrict__ Wcat,
    float* __restrict__ lsum, float* __restrict__ qn2r, float* __restrict__ kn2r)
{
    const int n_x = NB * SEQ * DIM, n_w = DIM * DIM;
    int gid = blockIdx.x * 256 + threadIdx.x;
    if (gid < NB * SEQ) { lsum[gid] = 0.f; qn2r[gid] = 0.f; kn2r[gid] = 0.f; }
    int i4 = gid * 4;
    if (i4 < n_x) {
        float4 v = *(const float4*)&x[i4];
        u16x4 h = {f2bf(v.x), f2bf(v.y), f2bf(v.z), f2bf(v.w)};
        *(u16x4*)&x_bf[i4] = h;
    } else if (i4 < n_x + 3 * n_w) {
        int j = i4 - n_x;
        const float* W = (j < n_w) ? Wq : (j < 2 * n_w ? Wk : Wv);
        int off = j % n_w;
        float4 v = *(const float4*)&W[off];
        u16x4 h = {f2bf(v.x), f2bf(v.y), f2bf(v.z), f2bf(v.w)};
        *(u16x4*)&Wcat[j] = h;
    }
}

// =====================================================================
// QKV GEMM: 128x128-tile, BK=64, single-buffer gl_lds 2-barrier (the
// empirically best structure). Outputs: qbuf[8192][512], kbuf[8192][512]
// (bf16, +bias), vT[b][d][s]; also atomicAdds raw row-norms of the bf16
// q/k values into qn2r/kn2r (replaces the project kernel entirely).
// =====================================================================
__global__ __launch_bounds__(256, 2) void gemm_qkv_kernel(
    const u16* __restrict__ A, const u16* __restrict__ Bt,
    u16* __restrict__ qbuf, u16* __restrict__ kbuf, u16* __restrict__ vT,
    const float* __restrict__ bq, const float* __restrict__ bk, const float* __restrict__ bv,
    float* __restrict__ qn2r, float* __restrict__ kn2r)
{
    const int lda = 512, ldb = 512;
    int bn = blockIdx.x, bm = blockIdx.y;

    __shared__ __align__(16) u16 As[128 * 64];
    __shared__ __align__(16) u16 Bs[128 * 64];

    int t = threadIdx.x, wave = t >> 6, lane = t & 63;
    int wr = wave >> 1, wc = wave & 1;
    int lrow = lane & 15, quad = lane >> 4;
    int srow = lane >> 3, sc8 = lane & 7;

    const u16* Ab = A + (size_t)(bm * 128) * lda;
    const u16* Bb = Bt + (size_t)(bn * 128) * ldb;

    float4e acc[4][4];
#pragma unroll
    for (int i = 0; i < 4; i++)
#pragma unroll
        for (int j = 0; j < 4; j++) acc[i][j] = (float4e){0.f, 0.f, 0.f, 0.f};

    for (int kt = 0; kt < 8; ++kt) {
        int k0 = kt << 6;
        __syncthreads();
#pragma unroll
        for (int h = 0; h < 4; ++h) {
            int q = wave * 4 + h;
            int row = q * 8 + srow;
            int c = sc8 ^ (row & 7);
            gl_lds16(Ab + (size_t)row * lda + k0 + c * 8, &As[q * 512]);
            gl_lds16(Bb + (size_t)row * ldb + k0 + c * 8, &Bs[q * 512]);
        }
        __syncthreads();
#pragma unroll
        for (int kk = 0; kk < 2; ++kk) {
            short8 af[4], bfr[4];
#pragma unroll
            for (int im = 0; im < 4; im++) {
                int R = wr * 64 + im * 16 + lrow;
                af[im] = *(const short8*)&As[R * 64 + (((kk * 4 + quad) ^ (R & 7)) * 8)];
            }
#pragma unroll
            for (int in = 0; in < 4; in++) {
                int R = wc * 64 + in * 16 + lrow;
                bfr[in] = *(const short8*)&Bs[R * 64 + (((kk * 4 + quad) ^ (R & 7)) * 8)];
            }
#pragma unroll
            for (int im = 0; im < 4; im++)
#pragma unroll
                for (int in = 0; in < 4; in++)
                    acc[im][in] = __builtin_amdgcn_mfma_f32_16x16x32_bf16(af[im], bfr[in], acc[im][in], 0, 0, 0);
        }
    }

    // epilogue — region is uniform per block (regions are 512-aligned, tiles 128)
    int region = bn >> 2;   // 0:q  1:k  2:v
    float nsum[4][4];
#pragma unroll
    for (int im = 0; im < 4; im++)
#pragma unroll
        for (int r = 0; r < 4; r++) nsum[im][r] = 0.f;

#pragma unroll
    for (int in = 0; in < 4; in++) {
        int gj = bn * 128 + wc * 64 + in * 16 + lrow;
        float bias = (gj < 512) ? bq[gj] : (gj < 1024 ? bk[gj - 512] : bv[gj - 1024]);
#pragma unroll
        for (int im = 0; im < 4; im++) {
            int gi0 = bm * 128 + wr * 64 + im * 16 + quad * 4;
            u16x4 pack;
#pragma unroll
            for (int r = 0; r < 4; r++) {
                u16 hv = f2bf(acc[im][in][r] + bias);
                pack[r] = hv;
                if (region == 0) {
                    qbuf[(size_t)(gi0 + r) * 512 + gj] = hv;
                } else if (region == 1) {
                    kbuf[(size_t)(gi0 + r) * 512 + (gj - 512)] = hv;
                }
                if (region < 2) { float vv = bf2f(hv); nsum[im][r] += vv * vv; }
            }
            if (region == 2) {   // vT[b][d][s], 4 consecutive s -> 8B store
                int bb = gi0 >> 11, s = gi0 & 2047;
                *(u16x4*)&vT[((size_t)bb * DIM + (gj - 1024)) * SEQ + s] = pack;
            }
        }
    }
    if (region < 2) {
        float* nrm = (region == 0) ? qn2r : kn2r;
#pragma unroll
        for (int im = 0; im < 4; im++)
#pragma unroll
            for (int r = 0; r < 4; r++) {
                float v = nsum[im][r];
                v += __shfl_xor(v, 1);
                v += __shfl_xor(v, 2);
                v += __shfl_xor(v, 4);
                v += __shfl_xor(v, 8);
                if (lrow == 0)
                    atomicAdd(&nrm[bm * 128 + wr * 64 + im * 16 + quad * 4 + r], v);
            }
    }
}

// =====================================================================
// Scores GEMM: 128x128-tile, single-buffer 2-barrier (R0's 53.5 µs
// structure). Reads raw bf16 qbuf/kbuf; projection applied as per-row
// scalar scales in the epilogue (dot_m = sclq*sclk*dot, qn = sclq^2*qr):
// mathematically identical to projecting first, one fewer bf16 rounding.
// =====================================================================
__global__ __launch_bounds__(256, 2) void gemm_scores_kernel(
    const u16* __restrict__ qbuf, const u16* __restrict__ kbuf,
    u16* __restrict__ attnH, float* __restrict__ lsum,
    const float* __restrict__ qn2r, const float* __restrict__ kn2r,
    const float* __restrict__ curvp, const float* __restrict__ tempp)
{
    const int lda = 512, ldb = 512, ldc = SEQ;
    int bn = blockIdx.x, bm = blockIdx.y, b = blockIdx.z;
    if (bn > bm) return;   // fully-masked 128x128 tile

    __shared__ __align__(16) u16 As[128 * 64];
    __shared__ __align__(16) u16 Bs[128 * 64];

    int t = threadIdx.x, wave = t >> 6, lane = t & 63;
    int wr = wave >> 1, wc = wave & 1;
    int lrow = lane & 15, quad = lane >> 4;
    int srow = lane >> 3, sc8 = lane & 7;

    const u16* Ab = qbuf + (size_t)(b * SEQ + bm * 128) * lda;
    const u16* Bb = kbuf + (size_t)(b * SEQ + bn * 128) * ldb;

    float4e acc[4][4];
#pragma unroll
    for (int i = 0; i < 4; i++)
#pragma unroll
        for (int j = 0; j < 4; j++) acc[i][j] = (float4e){0.f, 0.f, 0.f, 0.f};

    for (int kt = 0; kt < 8; ++kt) {
        int k0 = kt << 6;
        __syncthreads();
#pragma unroll
        for (int h = 0; h < 4; ++h) {
            int q = wave * 4 + h;
            int row = q * 8 + srow;
            int c = sc8 ^ (row & 7);
            gl_lds16(Ab + (size_t)row * lda + k0 + c * 8, &As[q * 512]);
            gl_lds16(Bb + (size_t)row * ldb + k0 + c * 8, &Bs[q * 512]);
        }
        __syncthreads();
#pragma unroll
        for (int kk = 0; kk < 2; ++kk) {
            short8 af[4], bfr[4];
#pragma unroll
            for (int im = 0; im < 4; im++) {
                int R = wr * 64 + im * 16 + lrow;
                af[im] = *(const short8*)&As[R * 64 + (((kk * 4 + quad) ^ (R & 7)) * 8)];
            }
#pragma unroll
            for (int in = 0; in < 4; in++) {
                int R = wc * 64 + in * 16 + lrow;
                bfr[in] = *(const short8*)&Bs[R * 64 + (((kk * 4 + quad) ^ (R & 7)) * 8)];
            }
#pragma unroll
            for (int im = 0; im < 4; im++)
#pragma unroll
                for (int in = 0; in < 4; in++)
                    acc[im][in] = __builtin_amdgcn_mfma_f32_16x16x32_bf16(af[im], bfr[in], acc[im][in], 0, 0, 0);
        }
    }

    float kv = curv_of(curvp[0]);
    float absk = fabsf(kv);
    float sk = sqrtf(fmaxf(absk, 1e-5f));
    bool euc = (absk < 0.01f);
    float mxn = (1.0f - 1e-3f) / sk;                 // Poincare max norm
    float invT = 1.0f / (tempp[0] + 1e-8f);
    float Cexp = -1.4426950408889634f * invT;        // e = exp2(dist * Cexp)
    u16* Cb = attnH + (size_t)b * SEQ * SEQ;

    // per-column projection scales
    float sclk[4], knp[4];
#pragma unroll
    for (int in = 0; in < 4; in++) {
        float kr = kn2r[b * SEQ + bn * 128 + wc * 64 + in * 16 + lrow];
        float nk = sqrtf(kr + 1e-12f);
        float s = euc ? 1.f : (kv < 0.f ? fminf(1.f, mxn / nk) : 1.f / (nk * sk));
        sclk[in] = s; knp[in] = kr * s * s;
    }

    float psum[4][4];
#pragma unroll
    for (int im = 0; im < 4; im++)
#pragma unroll
        for (int r = 0; r < 4; r++) psum[im][r] = 0.f;

#pragma unroll
    for (int im = 0; im < 4; im++) {
#pragma unroll
        for (int r = 0; r < 4; r++) {
            int gi = bm * 128 + wr * 64 + im * 16 + quad * 4 + r;
            float qr = qn2r[b * SEQ + gi];
            float nq = sqrtf(qr + 1e-12f);
            float sq_ = euc ? 1.f : (kv < 0.f ? fminf(1.f, mxn / nq) : 1.f / (nq * sk));
            float qn = qr * sq_ * sq_;
#pragma unroll
            for (int in = 0; in < 4; in++) {
                int gj = bn * 128 + wc * 64 + in * 16 + lrow;
                float dot = acc[im][in][r] * sq_ * sclk[in];
                float diff2 = fmaxf(qn + knp[in] - 2.f * dot, 0.f);
                float dist;
                if (euc) {
                    dist = sqrtf(diff2 + 1e-12f);
                } else if (kv < 0.f) {
                    float denom = fmaxf((1.f - absk * qn) * (1.f - absk * knp[in]), 1e-5f);
                    float arg = fmaxf(1.f + 2.f * absk * diff2 / denom, 1.f + 1e-7f);
                    dist = acoshf(arg) / sk;
                } else {
                    float c = fminf(fmaxf(absk * dot, -1.f + 1e-7f), 1.f - 1e-7f);
                    dist = acosf(c) / sk;
                }
                float e = (gj <= gi) ? exp2f(dist * Cexp) : 0.f;   // scores<=0 -> no max shift
                Cb[(size_t)gi * ldc + gj] = f2bf(e);
                psum[im][r] += e;
            }
        }
    }
#pragma unroll
    for (int im = 0; im < 4; im++)
#pragma unroll
        for (int r = 0; r < 4; r++) {
            float v = psum[im][r];
            v += __shfl_xor(v, 1);
            v += __shfl_xor(v, 2);
            v += __shfl_xor(v, 4);
            v += __shfl_xor(v, 8);
            if (lrow == 0) {
                int gi = bm * 128 + wr * 64 + im * 16 + quad * 4 + r;
                atomicAdd(&lsum[b * SEQ + gi], v);
            }
        }
}

// =====================================================================
// PV GEMM: 64x64, BK=64, single-buffer 2-barrier, full causal K per
// block, direct fp32 store with 1/l. FUSED attnF emission: block bn
// emits fp32 attnF for each staged A-tile with kt == bn (mod 8) and
// zero-fills its masked tiles. Replaces the norm_attn kernel.
// =====================================================================
__global__ __launch_bounds__(256, 4) void gemm_pv_kernel(
    const u16* __restrict__ attnH, const u16* __restrict__ vT,
    float* __restrict__ out, float* __restrict__ attnF,
    const float* __restrict__ lsum)
{
    const int lda = SEQ, ldb = SEQ, ldc = DIM;
    int bn = blockIdx.x, bm = blockIdx.y, b = blockIdx.z;

    __shared__ __align__(16) u16 As[64 * 64];
    __shared__ __align__(16) u16 Bs[64 * 64];

    int t = threadIdx.x, wave = t >> 6, lane = t & 63;
    int wr = wave >> 1, wc = wave & 1;
    int lrow = lane & 15, quad = lane >> 4;
    int srow = lane >> 3, sc = lane & 7;

    const u16* Ab = attnH + (size_t)b * SEQ * SEQ + (size_t)(bm * 64) * lda;
    const u16* Bb = vT + (size_t)b * DIM * SEQ + (size_t)(bn * 64) * ldb;
    float* attnFb = attnF + (size_t)b * SEQ * SEQ;

    // zero-fill the fully-masked attnF tiles owned by this bn
    {
        int r = t >> 2, c4 = t & 3;
        float4 z = (float4){0.f, 0.f, 0.f, 0.f};
        for (int kt = bm + 1; kt < 32; ++kt)
            if ((kt & 7) == bn) {
                float* dst = attnFb + (size_t)(bm * 64 + r) * SEQ + kt * 64 + c4 * 16;
                ((float4*)dst)[0] = z; ((float4*)dst)[1] = z;
                ((float4*)dst)[2] = z; ((float4*)dst)[3] = z;
            }
    }

    float4e acc[2][2];
#pragma unroll
    for (int i = 0; i < 2; i++)
#pragma unroll
        for (int j = 0; j < 2; j++) acc[i][j] = (float4e){0.f, 0.f, 0.f, 0.f};

    for (int kt = 0; kt <= bm; ++kt) {
        int k0 = kt << 6;
        __syncthreads();
#pragma unroll
        for (int h = 0; h < 2; ++h) {
            int q = wave * 2 + h;
            int row = q * 8 + srow;
            int c = sc ^ (row & 7);
            gl_lds16(Ab + (size_t)row * lda + k0 + c * 8, &As[q * 512]);
            gl_lds16(Bb + (size_t)row * ldb + k0 + c * 8, &Bs[q * 512]);
        }
        __syncthreads();
#pragma unroll
        for (int s = 0; s < 2; ++s) {
            short8 af[2], bfr[2];
#pragma unroll
            for (int im = 0; im < 2; im++) {
                int R = wr * 32 + im * 16 + lrow;
                af[im] = *(const short8*)&As[R * 64 + (((s * 4 + quad) ^ (R & 7)) * 8)];
            }
#pragma unroll
            for (int in = 0; in < 2; in++) {
                int R = wc * 32 + in * 16 + lrow;
                bfr[in] = *(const short8*)&Bs[R * 64 + (((s * 4 + quad) ^ (R & 7)) * 8)];
            }
#pragma unroll
            for (int im = 0; im < 2; im++)
#pragma unroll
                for (int in = 0; in < 2; in++)
                    acc[im][in] = __builtin_amdgcn_mfma_f32_16x16x32_bf16(af[im], bfr[in], acc[im][in], 0, 0, 0);
        }
        // fused attnF emission from the staged LDS A-tile (unique writer: bn == kt%8)
        if ((kt & 7) == bn) {
            int r = t >> 2, c4 = t & 3;
            int gi = bm * 64 + r;
            float invl = 1.0f / lsum[b * SEQ + gi];
            const u16* src = &As[r * 64];
            int j0 = c4 * 2;
            ushort8 u0 = *(const ushort8*)&src[(j0 ^ (r & 7)) * 8];
            ushort8 u1 = *(const ushort8*)&src[((j0 + 1) ^ (r & 7)) * 8];
            float* dst = attnFb + (size_t)gi * SEQ + kt * 64 + c4 * 16;
            float4 f0 = {bf2f(u0[0]) * invl, bf2f(u0[1]) * invl, bf2f(u0[2]) * invl, bf2f(u0[3]) * invl};
            float4 f1 = {bf2f(u0[4]) * invl, bf2f(u0[5]) * invl, bf2f(u0[6]) * invl, bf2f(u0[7]) * invl};
            float4 f2 = {bf2f(u1[0]) * invl, bf2f(u1[1]) * invl, bf2f(u1[2]) * invl, bf2f(u1[3]) * invl};
            float4 f3 = {bf2f(u1[4]) * invl, bf2f(u1[5]) * invl, bf2f(u1[6]) * invl, bf2f(u1[7]) * invl};
            ((float4*)dst)[0] = f0; ((float4*)dst)[1] = f1;
            ((float4*)dst)[2] = f2; ((float4*)dst)[3] = f3;
        }
    }

    float* Cb = out + (size_t)b * SEQ * DIM;
#pragma unroll
    for (int im = 0; im < 2; im++)
#pragma unroll
        for (int r = 0; r < 4; r++) {
            int gi = bm * 64 + wr * 32 + im * 16 + quad * 4 + r;
            float invl = 1.0f / lsum[b * SEQ + gi];
#pragma unroll
            for (int in = 0; in < 2; in++) {
                int gd = bn * 64 + wc * 32 + in * 16 + lrow;
                Cb[(size_t)gi * ldc + gd] = acc[im][in][r] * invl;
            }
        }
}

// ---------------- launch ----------------
extern "C" void kernel_launch(void* const* d_in, const int* in_sizes, int n_in,
                              void* d_out, int out_size, void* d_ws, size_t ws_size,
                              hipStream_t stream) {
    (void)in_sizes; (void)n_in; (void)out_size; (void)ws_size;

    const float* x    = (const float*)d_in[0];
    const float* Wq   = (const float*)d_in[1];
    const float* bq   = (const float*)d_in[2];
    const float* Wk   = (const float*)d_in[3];
    const float* bk   = (const float*)d_in[4];
    const float* Wv   = (const float*)d_in[5];
    const float* bv   = (const float*)d_in[6];
    const float* curv = (const float*)d_in[7];
    const float* temp = (const float*)d_in[8];

    float* out   = (float*)d_out;                       // [4][2048][512]
    float* attnF = out + (size_t)NB * SEQ * DIM;        // [4][2048][2048]

    char* ws = (char*)d_ws;
    // layout (bytes), peak 58.9 MB:
    //   0        attnH  33,554,432  (aliases x_bf@0 (8.4M) + Wcat@8388608
    //                                (1.5M) — both dead after QKV)
    //   33554432 qbuf    8,388,608  [8192][512] bf16 (dead after scores)
    //   41943040 kbuf    8,388,608  [8192][512] bf16 (dead after scores)
    //   50331648 vT      8,388,608  [4][512][2048] bf16
    //   58720256 qn2r       32,768  raw row-norms (bf16 values, f32 sums)
    //   58753024 kn2r       32,768
    //   58785792 lsum       32,768
    u16*   x_bf  = (u16*)(ws + 0);
    u16*   Wcat  = (u16*)(ws + 8388608);
    u16*   attnH = (u16*)(ws + 0);
    u16*   qbuf  = (u16*)(ws + 33554432);
    u16*   kbuf  = (u16*)(ws + 41943040);
    u16*   vT    = (u16*)(ws + 50331648);
    float* qn2r  = (float*)(ws + 58720256);
    float* kn2r  = (float*)(ws + 58753024);
    float* lsum  = (float*)(ws + 58785792);

    // K0: conversions + zero lsum/qn2r/kn2r
    {
        int n_tot = (NB * SEQ * DIM + 3 * DIM * DIM) / 4;
        cvt_all_kernel<<<(n_tot + 255) / 256, 256, 0, stream>>>(
            x, Wq, Wk, Wv, x_bf, Wcat, lsum, qn2r, kn2r);
    }

    // K1: QKV GEMM (M=8192, N=1536, K=512) + bias + vT + raw row-norms
    gemm_qkv_kernel<<<dim3(1536 / 128, 8192 / 128, 1), 256, 0, stream>>>(
        x_bf, Wcat, qbuf, kbuf, vT, bq, bk, bv, qn2r, kn2r);

    // K2: scores + inline projection scales + dist + exp + row sums
    gemm_scores_kernel<<<dim3(SEQ / 128, SEQ / 128, NB), 256, 0, stream>>>(
        qbuf, kbuf, attnH, lsum, qn2r, kn2r, curv, temp);

    // K3: PV full causal K per block, direct store with 1/l, fused attnF
    gemm_pv_kernel<<<dim3(DIM / 64, SEQ / 64, NB), 256, 0, stream>>>(
        attnH, vT, out, attnF, lsum);
}

// Round 6
// 238.946 us; speedup vs baseline: 1.7773x; 1.1549x over previous
//
#include <hip/hip_runtime.h>
#include <hip/hip_bf16.h>
#include <math.h>

typedef unsigned short u16;
typedef float float4e __attribute__((ext_vector_type(4)));
typedef short short8 __attribute__((ext_vector_type(8)));
typedef unsigned short ushort8 __attribute__((ext_vector_type(8)));
typedef unsigned short u16x4 __attribute__((ext_vector_type(4)));

#define SEQ 2048
#define DIM 512
#define NB  4

__device__ __forceinline__ float bf2f(u16 h) {
    return __uint_as_float(((unsigned)h) << 16);
}
__device__ __forceinline__ u16 f2bf(float f) {
    __hip_bfloat16 h = __float2bfloat16(f);
    return *reinterpret_cast<u16*>(&h);
}
__device__ __forceinline__ float curv_of(float raw) {
    return -2.0f + 2.0f * (tanhf(raw) + 1.0f);   // bounds (-2,2)
}
// async global->LDS, 16B per lane; lds base wave-uniform (lane lands at base+lane*16)
__device__ __forceinline__ void gl_lds16(const u16* g, u16* lds) {
    __builtin_amdgcn_global_load_lds(
        (const __attribute__((address_space(1))) unsigned int*)g,
        (__attribute__((address_space(3))) unsigned int*)lds, 16, 0, 0);
}

// ---------------- fused conversions + zero lsum/qn2r/kn2r ----------------
__global__ __launch_bounds__(256) void cvt_all_kernel(
    const float* __restrict__ x, const float* __restrict__ Wq,
    const float* __restrict__ Wk, const float* __restrict__ Wv,
    u16* __restrict__ x_bf, u16* __restrict__ Wcat,
    float* __restrict__ lsum, float* __restrict__ qn2r, float* __restrict__ kn2r)
{
    const int n_x = NB * SEQ * DIM, n_w = DIM * DIM;
    int gid = blockIdx.x * 256 + threadIdx.x;
    if (gid < NB * SEQ) { lsum[gid] = 0.f; qn2r[gid] = 0.f; kn2r[gid] = 0.f; }
    int i4 = gid * 4;
    if (i4 < n_x) {
        float4 v = *(const float4*)&x[i4];
        u16x4 h = {f2bf(v.x), f2bf(v.y), f2bf(v.z), f2bf(v.w)};
        *(u16x4*)&x_bf[i4] = h;
    } else if (i4 < n_x + 3 * n_w) {
        int j = i4 - n_x;
        const float* W = (j < n_w) ? Wq : (j < 2 * n_w ? Wk : Wv);
        int off = j % n_w;
        float4 v = *(const float4*)&W[off];
        u16x4 h = {f2bf(v.x), f2bf(v.y), f2bf(v.z), f2bf(v.w)};
        *(u16x4*)&Wcat[j] = h;
    }
}

// =====================================================================
// QKV GEMM: 128x128-tile, BK=64, single-buffer gl_lds 2-barrier.
// Outputs: qbuf[8192][512], kbuf[8192][512] (bf16, +bias), vT[b][d][s];
// atomicAdds raw row-norms of the bf16 q/k values into qn2r/kn2r.
// =====================================================================
__global__ __launch_bounds__(256, 2) void gemm_qkv_kernel(
    const u16* __restrict__ A, const u16* __restrict__ Bt,
    u16* __restrict__ qbuf, u16* __restrict__ kbuf, u16* __restrict__ vT,
    const float* __restrict__ bq, const float* __restrict__ bk, const float* __restrict__ bv,
    float* __restrict__ qn2r, float* __restrict__ kn2r)
{
    const int lda = 512, ldb = 512;
    int bn = blockIdx.x, bm = blockIdx.y;

    __shared__ __align__(16) u16 As[128 * 64];
    __shared__ __align__(16) u16 Bs[128 * 64];

    int t = threadIdx.x, wave = t >> 6, lane = t & 63;
    int wr = wave >> 1, wc = wave & 1;
    int lrow = lane & 15, quad = lane >> 4;
    int srow = lane >> 3, sc8 = lane & 7;

    const u16* Ab = A + (size_t)(bm * 128) * lda;
    const u16* Bb = Bt + (size_t)(bn * 128) * ldb;

    float4e acc[4][4];
#pragma unroll
    for (int i = 0; i < 4; i++)
#pragma unroll
        for (int j = 0; j < 4; j++) acc[i][j] = (float4e){0.f, 0.f, 0.f, 0.f};

    for (int kt = 0; kt < 8; ++kt) {
        int k0 = kt << 6;
        __syncthreads();
#pragma unroll
        for (int h = 0; h < 4; ++h) {
            int q = wave * 4 + h;
            int row = q * 8 + srow;
            int c = sc8 ^ (row & 7);
            gl_lds16(Ab + (size_t)row * lda + k0 + c * 8, &As[q * 512]);
            gl_lds16(Bb + (size_t)row * ldb + k0 + c * 8, &Bs[q * 512]);
        }
        __syncthreads();
#pragma unroll
        for (int kk = 0; kk < 2; ++kk) {
            short8 af[4], bfr[4];
#pragma unroll
            for (int im = 0; im < 4; im++) {
                int R = wr * 64 + im * 16 + lrow;
                af[im] = *(const short8*)&As[R * 64 + (((kk * 4 + quad) ^ (R & 7)) * 8)];
            }
#pragma unroll
            for (int in = 0; in < 4; in++) {
                int R = wc * 64 + in * 16 + lrow;
                bfr[in] = *(const short8*)&Bs[R * 64 + (((kk * 4 + quad) ^ (R & 7)) * 8)];
            }
#pragma unroll
            for (int im = 0; im < 4; im++)
#pragma unroll
                for (int in = 0; in < 4; in++)
                    acc[im][in] = __builtin_amdgcn_mfma_f32_16x16x32_bf16(af[im], bfr[in], acc[im][in], 0, 0, 0);
        }
    }

    // epilogue — region is uniform per block (regions are 512-aligned, tiles 128)
    int region = bn >> 2;   // 0:q  1:k  2:v
    float nsum[4][4];
#pragma unroll
    for (int im = 0; im < 4; im++)
#pragma unroll
        for (int r = 0; r < 4; r++) nsum[im][r] = 0.f;

#pragma unroll
    for (int in = 0; in < 4; in++) {
        int gj = bn * 128 + wc * 64 + in * 16 + lrow;
        float bias = (gj < 512) ? bq[gj] : (gj < 1024 ? bk[gj - 512] : bv[gj - 1024]);
#pragma unroll
        for (int im = 0; im < 4; im++) {
            int gi0 = bm * 128 + wr * 64 + im * 16 + quad * 4;
            u16x4 pack;
#pragma unroll
            for (int r = 0; r < 4; r++) {
                u16 hv = f2bf(acc[im][in][r] + bias);
                pack[r] = hv;
                if (region == 0) {
                    qbuf[(size_t)(gi0 + r) * 512 + gj] = hv;
                } else if (region == 1) {
                    kbuf[(size_t)(gi0 + r) * 512 + (gj - 512)] = hv;
                }
                if (region < 2) { float vv = bf2f(hv); nsum[im][r] += vv * vv; }
            }
            if (region == 2) {   // vT[b][d][s], 4 consecutive s -> 8B store
                int bb = gi0 >> 11, s = gi0 & 2047;
                *(u16x4*)&vT[((size_t)bb * DIM + (gj - 1024)) * SEQ + s] = pack;
            }
        }
    }
    if (region < 2) {
        float* nrm = (region == 0) ? qn2r : kn2r;
#pragma unroll
        for (int im = 0; im < 4; im++)
#pragma unroll
            for (int r = 0; r < 4; r++) {
                float v = nsum[im][r];
                v += __shfl_xor(v, 1);
                v += __shfl_xor(v, 2);
                v += __shfl_xor(v, 4);
                v += __shfl_xor(v, 8);
                if (lrow == 0)
                    atomicAdd(&nrm[bm * 128 + wr * 64 + im * 16 + quad * 4 + r], v);
            }
    }
}

// =====================================================================
// Row projection scales: per row precompute {projected_norm^2, scale} so
// the scores epilogue is pure loads (no sqrt/div chains). 8192 rows.
// =====================================================================
__global__ __launch_bounds__(256) void rownorm_kernel(
    const float* __restrict__ qn2r, const float* __restrict__ kn2r,
    float2* __restrict__ qpk, float2* __restrict__ kpk,
    const float* __restrict__ curvp)
{
    int i = blockIdx.x * 256 + threadIdx.x;   // [0, 8192)
    float kv = curv_of(curvp[0]);
    float absk = fabsf(kv);
    float sk = sqrtf(fmaxf(absk, 1e-5f));
    bool euc = (absk < 0.01f);
    float mxn = (1.0f - 1e-3f) / sk;

    float qr = qn2r[i];
    float nq = sqrtf(qr + 1e-12f);
    float sq_ = euc ? 1.f : (kv < 0.f ? fminf(1.f, mxn / nq) : 1.f / (nq * sk));
    qpk[i] = make_float2(qr * sq_ * sq_, sq_);

    float kr = kn2r[i];
    float nk = sqrtf(kr + 1e-12f);
    float sk_ = euc ? 1.f : (kv < 0.f ? fminf(1.f, mxn / nk) : 1.f / (nk * sk));
    kpk[i] = make_float2(kr * sk_ * sk_, sk_);
}

// =====================================================================
// Scores GEMM: 128x128-tile, single-buffer 2-barrier (R0's structure).
// Raw bf16 qbuf/kbuf MFMA; epilogue applies precomputed per-row
// {norm^2, scale} float2s (pure loads, R0-style) + dist + exp2 + lsum.
// =====================================================================
__global__ __launch_bounds__(256, 2) void gemm_scores_kernel(
    const u16* __restrict__ qbuf, const u16* __restrict__ kbuf,
    u16* __restrict__ attnH, float* __restrict__ lsum,
    const float2* __restrict__ qpk, const float2* __restrict__ kpk,
    const float* __restrict__ curvp, const float* __restrict__ tempp)
{
    const int lda = 512, ldb = 512, ldc = SEQ;
    int bn = blockIdx.x, bm = blockIdx.y, b = blockIdx.z;
    if (bn > bm) return;   // fully-masked 128x128 tile

    __shared__ __align__(16) u16 As[128 * 64];
    __shared__ __align__(16) u16 Bs[128 * 64];

    int t = threadIdx.x, wave = t >> 6, lane = t & 63;
    int wr = wave >> 1, wc = wave & 1;
    int lrow = lane & 15, quad = lane >> 4;
    int srow = lane >> 3, sc8 = lane & 7;

    const u16* Ab = qbuf + (size_t)(b * SEQ + bm * 128) * lda;
    const u16* Bb = kbuf + (size_t)(b * SEQ + bn * 128) * ldb;

    float4e acc[4][4];
#pragma unroll
    for (int i = 0; i < 4; i++)
#pragma unroll
        for (int j = 0; j < 4; j++) acc[i][j] = (float4e){0.f, 0.f, 0.f, 0.f};

    for (int kt = 0; kt < 8; ++kt) {
        int k0 = kt << 6;
        __syncthreads();
#pragma unroll
        for (int h = 0; h < 4; ++h) {
            int q = wave * 4 + h;
            int row = q * 8 + srow;
            int c = sc8 ^ (row & 7);
            gl_lds16(Ab + (size_t)row * lda + k0 + c * 8, &As[q * 512]);
            gl_lds16(Bb + (size_t)row * ldb + k0 + c * 8, &Bs[q * 512]);
        }
        __syncthreads();
#pragma unroll
        for (int kk = 0; kk < 2; ++kk) {
            short8 af[4], bfr[4];
#pragma unroll
            for (int im = 0; im < 4; im++) {
                int R = wr * 64 + im * 16 + lrow;
                af[im] = *(const short8*)&As[R * 64 + (((kk * 4 + quad) ^ (R & 7)) * 8)];
            }
#pragma unroll
            for (int in = 0; in < 4; in++) {
                int R = wc * 64 + in * 16 + lrow;
                bfr[in] = *(const short8*)&Bs[R * 64 + (((kk * 4 + quad) ^ (R & 7)) * 8)];
            }
#pragma unroll
            for (int im = 0; im < 4; im++)
#pragma unroll
                for (int in = 0; in < 4; in++)
                    acc[im][in] = __builtin_amdgcn_mfma_f32_16x16x32_bf16(af[im], bfr[in], acc[im][in], 0, 0, 0);
        }
    }

    float kv = curv_of(curvp[0]);
    float absk = fabsf(kv);
    float sk = sqrtf(fmaxf(absk, 1e-5f));
    bool euc = (absk < 0.01f);
    float invT = 1.0f / (tempp[0] + 1e-8f);
    float Cexp = -1.4426950408889634f * invT;        // e = exp2(dist * Cexp)
    u16* Cb = attnH + (size_t)b * SEQ * SEQ;

    // per-column {projected norm^2, scale} — pure loads
    float2 kp[4];
#pragma unroll
    for (int in = 0; in < 4; in++)
        kp[in] = kpk[b * SEQ + bn * 128 + wc * 64 + in * 16 + lrow];

    float psum[4][4];
#pragma unroll
    for (int im = 0; im < 4; im++)
#pragma unroll
        for (int r = 0; r < 4; r++) psum[im][r] = 0.f;

#pragma unroll
    for (int im = 0; im < 4; im++) {
#pragma unroll
        for (int r = 0; r < 4; r++) {
            int gi = bm * 128 + wr * 64 + im * 16 + quad * 4 + r;
            float2 qp = qpk[b * SEQ + gi];
            float qn = qp.x;
#pragma unroll
            for (int in = 0; in < 4; in++) {
                int gj = bn * 128 + wc * 64 + in * 16 + lrow;
                float kn = kp[in].x;
                float dot = acc[im][in][r] * qp.y * kp[in].y;
                float diff2 = fmaxf(qn + kn - 2.f * dot, 0.f);
                float dist;
                if (euc) {
                    dist = sqrtf(diff2 + 1e-12f);
                } else if (kv < 0.f) {
                    float denom = fmaxf((1.f - absk * qn) * (1.f - absk * kn), 1e-5f);
                    float arg = fmaxf(1.f + 2.f * absk * diff2 / denom, 1.f + 1e-7f);
                    dist = acoshf(arg) / sk;
                } else {
                    float c = fminf(fmaxf(absk * dot, -1.f + 1e-7f), 1.f - 1e-7f);
                    dist = acosf(c) / sk;
                }
                float e = (gj <= gi) ? exp2f(dist * Cexp) : 0.f;   // scores<=0 -> no max shift
                Cb[(size_t)gi * ldc + gj] = f2bf(e);
                psum[im][r] += e;
            }
        }
    }
#pragma unroll
    for (int im = 0; im < 4; im++)
#pragma unroll
        for (int r = 0; r < 4; r++) {
            float v = psum[im][r];
            v += __shfl_xor(v, 1);
            v += __shfl_xor(v, 2);
            v += __shfl_xor(v, 4);
            v += __shfl_xor(v, 8);
            if (lrow == 0) {
                int gi = bm * 128 + wr * 64 + im * 16 + quad * 4 + r;
                atomicAdd(&lsum[b * SEQ + gi], v);
            }
        }
}

// =====================================================================
// PV GEMM: 64x64, BK=64, single-buffer 2-barrier, full causal K per
// block, direct fp32 store with 1/l. FUSED attnF emission: block bn
// emits fp32 attnF for each staged A-tile with kt == bn (mod 8) and
// zero-fills its masked tiles. Replaces the norm_attn kernel.
// =====================================================================
__global__ __launch_bounds__(256, 4) void gemm_pv_kernel(
    const u16* __restrict__ attnH, const u16* __restrict__ vT,
    float* __restrict__ out, float* __restrict__ attnF,
    const float* __restrict__ lsum)
{
    const int lda = SEQ, ldb = SEQ, ldc = DIM;
    int bn = blockIdx.x, bm = blockIdx.y, b = blockIdx.z;

    __shared__ __align__(16) u16 As[64 * 64];
    __shared__ __align__(16) u16 Bs[64 * 64];

    int t = threadIdx.x, wave = t >> 6, lane = t & 63;
    int wr = wave >> 1, wc = wave & 1;
    int lrow = lane & 15, quad = lane >> 4;
    int srow = lane >> 3, sc = lane & 7;

    const u16* Ab = attnH + (size_t)b * SEQ * SEQ + (size_t)(bm * 64) * lda;
    const u16* Bb = vT + (size_t)b * DIM * SEQ + (size_t)(bn * 64) * ldb;
    float* attnFb = attnF + (size_t)b * SEQ * SEQ;

    // zero-fill the fully-masked attnF tiles owned by this bn
    {
        int r = t >> 2, c4 = t & 3;
        float4 z = (float4){0.f, 0.f, 0.f, 0.f};
        for (int kt = bm + 1; kt < 32; ++kt)
            if ((kt & 7) == bn) {
                float* dst = attnFb + (size_t)(bm * 64 + r) * SEQ + kt * 64 + c4 * 16;
                ((float4*)dst)[0] = z; ((float4*)dst)[1] = z;
                ((float4*)dst)[2] = z; ((float4*)dst)[3] = z;
            }
    }

    float4e acc[2][2];
#pragma unroll
    for (int i = 0; i < 2; i++)
#pragma unroll
        for (int j = 0; j < 2; j++) acc[i][j] = (float4e){0.f, 0.f, 0.f, 0.f};

    for (int kt = 0; kt <= bm; ++kt) {
        int k0 = kt << 6;
        __syncthreads();
#pragma unroll
        for (int h = 0; h < 2; ++h) {
            int q = wave * 2 + h;
            int row = q * 8 + srow;
            int c = sc ^ (row & 7);
            gl_lds16(Ab + (size_t)row * lda + k0 + c * 8, &As[q * 512]);
            gl_lds16(Bb + (size_t)row * ldb + k0 + c * 8, &Bs[q * 512]);
        }
        __syncthreads();
#pragma unroll
        for (int s = 0; s < 2; ++s) {
            short8 af[2], bfr[2];
#pragma unroll
            for (int im = 0; im < 2; im++) {
                int R = wr * 32 + im * 16 + lrow;
                af[im] = *(const short8*)&As[R * 64 + (((s * 4 + quad) ^ (R & 7)) * 8)];
            }
#pragma unroll
            for (int in = 0; in < 2; in++) {
                int R = wc * 32 + in * 16 + lrow;
                bfr[in] = *(const short8*)&Bs[R * 64 + (((s * 4 + quad) ^ (R & 7)) * 8)];
            }
#pragma unroll
            for (int im = 0; im < 2; im++)
#pragma unroll
                for (int in = 0; in < 2; in++)
                    acc[im][in] = __builtin_amdgcn_mfma_f32_16x16x32_bf16(af[im], bfr[in], acc[im][in], 0, 0, 0);
        }
        // fused attnF emission from the staged LDS A-tile (unique writer: bn == kt%8)
        if ((kt & 7) == bn) {
            int r = t >> 2, c4 = t & 3;
            int gi = bm * 64 + r;
            float invl = 1.0f / lsum[b * SEQ + gi];
            const u16* src = &As[r * 64];
            int j0 = c4 * 2;
            ushort8 u0 = *(const ushort8*)&src[(j0 ^ (r & 7)) * 8];
            ushort8 u1 = *(const ushort8*)&src[((j0 + 1) ^ (r & 7)) * 8];
            float* dst = attnFb + (size_t)gi * SEQ + kt * 64 + c4 * 16;
            float4 f0 = {bf2f(u0[0]) * invl, bf2f(u0[1]) * invl, bf2f(u0[2]) * invl, bf2f(u0[3]) * invl};
            float4 f1 = {bf2f(u0[4]) * invl, bf2f(u0[5]) * invl, bf2f(u0[6]) * invl, bf2f(u0[7]) * invl};
            float4 f2 = {bf2f(u1[0]) * invl, bf2f(u1[1]) * invl, bf2f(u1[2]) * invl, bf2f(u1[3]) * invl};
            float4 f3 = {bf2f(u1[4]) * invl, bf2f(u1[5]) * invl, bf2f(u1[6]) * invl, bf2f(u1[7]) * invl};
            ((float4*)dst)[0] = f0; ((float4*)dst)[1] = f1;
            ((float4*)dst)[2] = f2; ((float4*)dst)[3] = f3;
        }
    }

    float* Cb = out + (size_t)b * SEQ * DIM;
#pragma unroll
    for (int im = 0; im < 2; im++)
#pragma unroll
        for (int r = 0; r < 4; r++) {
            int gi = bm * 64 + wr * 32 + im * 16 + quad * 4 + r;
            float invl = 1.0f / lsum[b * SEQ + gi];
#pragma unroll
            for (int in = 0; in < 2; in++) {
                int gd = bn * 64 + wc * 32 + in * 16 + lrow;
                Cb[(size_t)gi * ldc + gd] = acc[im][in][r] * invl;
            }
        }
}

// ---------------- launch ----------------
extern "C" void kernel_launch(void* const* d_in, const int* in_sizes, int n_in,
                              void* d_out, int out_size, void* d_ws, size_t ws_size,
                              hipStream_t stream) {
    (void)in_sizes; (void)n_in; (void)out_size; (void)ws_size;

    const float* x    = (const float*)d_in[0];
    const float* Wq   = (const float*)d_in[1];
    const float* bq   = (const float*)d_in[2];
    const float* Wk   = (const float*)d_in[3];
    const float* bk   = (const float*)d_in[4];
    const float* Wv   = (const float*)d_in[5];
    const float* bv   = (const float*)d_in[6];
    const float* curv = (const float*)d_in[7];
    const float* temp = (const float*)d_in[8];

    float* out   = (float*)d_out;                       // [4][2048][512]
    float* attnF = out + (size_t)NB * SEQ * DIM;        // [4][2048][2048]

    char* ws = (char*)d_ws;
    // layout (bytes), peak 58.95 MB:
    //   0        attnH  33,554,432  (aliases x_bf@0 (8.4M) + Wcat@8388608
    //                                (1.5M) — both dead after QKV)
    //   33554432 qbuf    8,388,608  [8192][512] bf16
    //   41943040 kbuf    8,388,608  [8192][512] bf16
    //   50331648 vT      8,388,608  [4][512][2048] bf16
    //   58720256 qn2r       32,768  raw row-norm sums (f32)
    //   58753024 kn2r       32,768
    //   58785792 lsum       32,768
    //   58818560 qpk        65,536  float2 {proj norm^2, scale}
    //   58884096 kpk        65,536
    u16*   x_bf  = (u16*)(ws + 0);
    u16*   Wcat  = (u16*)(ws + 8388608);
    u16*   attnH = (u16*)(ws + 0);
    u16*   qbuf  = (u16*)(ws + 33554432);
    u16*   kbuf  = (u16*)(ws + 41943040);
    u16*   vT    = (u16*)(ws + 50331648);
    float* qn2r  = (float*)(ws + 58720256);
    float* kn2r  = (float*)(ws + 58753024);
    float* lsum  = (float*)(ws + 58785792);
    float2* qpk  = (float2*)(ws + 58818560);
    float2* kpk  = (float2*)(ws + 58884096);

    // K0: conversions + zero lsum/qn2r/kn2r
    {
        int n_tot = (NB * SEQ * DIM + 3 * DIM * DIM) / 4;
        cvt_all_kernel<<<(n_tot + 255) / 256, 256, 0, stream>>>(
            x, Wq, Wk, Wv, x_bf, Wcat, lsum, qn2r, kn2r);
    }

    // K1: QKV GEMM (M=8192, N=1536, K=512) + bias + vT + raw row-norms
    gemm_qkv_kernel<<<dim3(1536 / 128, 8192 / 128, 1), 256, 0, stream>>>(
        x_bf, Wcat, qbuf, kbuf, vT, bq, bk, bv, qn2r, kn2r);

    // K1.5: per-row projection scales (pure-load epilogue for scores)
    rownorm_kernel<<<NB * SEQ / 256, 256, 0, stream>>>(qn2r, kn2r, qpk, kpk, curv);

    // K2: scores + dist + exp (unnormalized bf16) + row sums
    gemm_scores_kernel<<<dim3(SEQ / 128, SEQ / 128, NB), 256, 0, stream>>>(
        qbuf, kbuf, attnH, lsum, qpk, kpk, curv, temp);

    // K3: PV full causal K per block, direct store with 1/l, fused attnF
    gemm_pv_kernel<<<dim3(DIM / 64, SEQ / 64, NB), 256, 0, stream>>>(
        attnH, vT, out, attnF, lsum);
}

// Round 7
// 234.044 us; speedup vs baseline: 1.8145x; 1.0209x over previous
//
#include <hip/hip_runtime.h>
#include <hip/hip_bf16.h>
#include <math.h>

typedef unsigned short u16;
typedef float float4e __attribute__((ext_vector_type(4)));
typedef short short8 __attribute__((ext_vector_type(8)));
typedef unsigned short ushort8 __attribute__((ext_vector_type(8)));
typedef unsigned short u16x4 __attribute__((ext_vector_type(4)));

#define SEQ 2048
#define DIM 512
#define NB  4

__device__ __forceinline__ float bf2f(u16 h) {
    return __uint_as_float(((unsigned)h) << 16);
}
__device__ __forceinline__ u16 f2bf(float f) {
    __hip_bfloat16 h = __float2bfloat16(f);
    return *reinterpret_cast<u16*>(&h);
}
__device__ __forceinline__ float curv_of(float raw) {
    return -2.0f + 2.0f * (tanhf(raw) + 1.0f);   // bounds (-2,2)
}
// async global->LDS, 16B per lane; lds base wave-uniform (lane lands at base+lane*16)
__device__ __forceinline__ void gl_lds16(const u16* g, u16* lds) {
    __builtin_amdgcn_global_load_lds(
        (const __attribute__((address_space(1))) unsigned int*)g,
        (__attribute__((address_space(3))) unsigned int*)lds, 16, 0, 0);
}

// ---------------- fused conversions + zero lsum/qn2r/kn2r ----------------
__global__ __launch_bounds__(256) void cvt_all_kernel(
    const float* __restrict__ x, const float* __restrict__ Wq,
    const float* __restrict__ Wk, const float* __restrict__ Wv,
    u16* __restrict__ x_bf, u16* __restrict__ Wcat,
    float* __restrict__ lsum, float* __restrict__ qn2r, float* __restrict__ kn2r)
{
    const int n_x = NB * SEQ * DIM, n_w = DIM * DIM;
    int gid = blockIdx.x * 256 + threadIdx.x;
    if (gid < NB * SEQ) { lsum[gid] = 0.f; qn2r[gid] = 0.f; kn2r[gid] = 0.f; }
    int i4 = gid * 4;
    if (i4 < n_x) {
        float4 v = *(const float4*)&x[i4];
        u16x4 h = {f2bf(v.x), f2bf(v.y), f2bf(v.z), f2bf(v.w)};
        *(u16x4*)&x_bf[i4] = h;
    } else if (i4 < n_x + 3 * n_w) {
        int j = i4 - n_x;
        const float* W = (j < n_w) ? Wq : (j < 2 * n_w ? Wk : Wv);
        int off = j % n_w;
        float4 v = *(const float4*)&W[off];
        u16x4 h = {f2bf(v.x), f2bf(v.y), f2bf(v.z), f2bf(v.w)};
        *(u16x4*)&Wcat[j] = h;
    }
}

// =====================================================================
// QKV GEMM: 128x128-tile, BK=64, single-buffer gl_lds 2-barrier.
// XCD-swizzled flat grid: xcd = n&7 (dispatch round-robins XCDs); each
// XCD owns 8 bm-strips -> x_bf strip (131KB) + Wcat (1.5MB) stay in its
// private L2 across the strip's 12 bn-blocks.
// Outputs: qbuf/kbuf (bf16, +bias), vT[b][d][s]; atomicAdds raw row-norms.
// =====================================================================
__global__ __launch_bounds__(256, 2) void gemm_qkv_kernel(
    const u16* __restrict__ A, const u16* __restrict__ Bt,
    u16* __restrict__ qbuf, u16* __restrict__ kbuf, u16* __restrict__ vT,
    const float* __restrict__ bq, const float* __restrict__ bk, const float* __restrict__ bv,
    float* __restrict__ qn2r, float* __restrict__ kn2r)
{
    const int lda = 512, ldb = 512;
    // flat grid 768: xcd = n&7, i = n>>3 in [0,96): bn = i%12, bm = xcd + 8*(i/12)
    int n = blockIdx.x;
    int xcd = n & 7, i = n >> 3;
    int bn = i % 12, bm = xcd + 8 * (i / 12);

    __shared__ __align__(16) u16 As[128 * 64];
    __shared__ __align__(16) u16 Bs[128 * 64];

    int t = threadIdx.x, wave = t >> 6, lane = t & 63;
    int wr = wave >> 1, wc = wave & 1;
    int lrow = lane & 15, quad = lane >> 4;
    int srow = lane >> 3, sc8 = lane & 7;

    const u16* Ab = A + (size_t)(bm * 128) * lda;
    const u16* Bb = Bt + (size_t)(bn * 128) * ldb;

    float4e acc[4][4];
#pragma unroll
    for (int i2 = 0; i2 < 4; i2++)
#pragma unroll
        for (int j = 0; j < 4; j++) acc[i2][j] = (float4e){0.f, 0.f, 0.f, 0.f};

    for (int kt = 0; kt < 8; ++kt) {
        int k0 = kt << 6;
        __syncthreads();
#pragma unroll
        for (int h = 0; h < 4; ++h) {
            int q = wave * 4 + h;
            int row = q * 8 + srow;
            int c = sc8 ^ (row & 7);
            gl_lds16(Ab + (size_t)row * lda + k0 + c * 8, &As[q * 512]);
            gl_lds16(Bb + (size_t)row * ldb + k0 + c * 8, &Bs[q * 512]);
        }
        __syncthreads();
#pragma unroll
        for (int kk = 0; kk < 2; ++kk) {
            short8 af[4], bfr[4];
#pragma unroll
            for (int im = 0; im < 4; im++) {
                int R = wr * 64 + im * 16 + lrow;
                af[im] = *(const short8*)&As[R * 64 + (((kk * 4 + quad) ^ (R & 7)) * 8)];
            }
#pragma unroll
            for (int in = 0; in < 4; in++) {
                int R = wc * 64 + in * 16 + lrow;
                bfr[in] = *(const short8*)&Bs[R * 64 + (((kk * 4 + quad) ^ (R & 7)) * 8)];
            }
#pragma unroll
            for (int im = 0; im < 4; im++)
#pragma unroll
                for (int in = 0; in < 4; in++)
                    acc[im][in] = __builtin_amdgcn_mfma_f32_16x16x32_bf16(af[im], bfr[in], acc[im][in], 0, 0, 0);
        }
    }

    // epilogue — region is uniform per block (regions are 512-aligned, tiles 128)
    int region = bn >> 2;   // 0:q  1:k  2:v
    float nsum[4][4];
#pragma unroll
    for (int im = 0; im < 4; im++)
#pragma unroll
        for (int r = 0; r < 4; r++) nsum[im][r] = 0.f;

#pragma unroll
    for (int in = 0; in < 4; in++) {
        int gj = bn * 128 + wc * 64 + in * 16 + lrow;
        float bias = (gj < 512) ? bq[gj] : (gj < 1024 ? bk[gj - 512] : bv[gj - 1024]);
#pragma unroll
        for (int im = 0; im < 4; im++) {
            int gi0 = bm * 128 + wr * 64 + im * 16 + quad * 4;
            u16x4 pack;
#pragma unroll
            for (int r = 0; r < 4; r++) {
                u16 hv = f2bf(acc[im][in][r] + bias);
                pack[r] = hv;
                if (region == 0) {
                    qbuf[(size_t)(gi0 + r) * 512 + gj] = hv;
                } else if (region == 1) {
                    kbuf[(size_t)(gi0 + r) * 512 + (gj - 512)] = hv;
                }
                if (region < 2) { float vv = bf2f(hv); nsum[im][r] += vv * vv; }
            }
            if (region == 2) {   // vT[b][d][s], 4 consecutive s -> 8B store
                int bb = gi0 >> 11, s = gi0 & 2047;
                *(u16x4*)&vT[((size_t)bb * DIM + (gj - 1024)) * SEQ + s] = pack;
            }
        }
    }
    if (region < 2) {
        float* nrm = (region == 0) ? qn2r : kn2r;
#pragma unroll
        for (int im = 0; im < 4; im++)
#pragma unroll
            for (int r = 0; r < 4; r++) {
                float v = nsum[im][r];
                v += __shfl_xor(v, 1);
                v += __shfl_xor(v, 2);
                v += __shfl_xor(v, 4);
                v += __shfl_xor(v, 8);
                if (lrow == 0)
                    atomicAdd(&nrm[bm * 128 + wr * 64 + im * 16 + quad * 4 + r], v);
            }
    }
}

// =====================================================================
// Row projection scales: per row precompute {projected_norm^2, scale}.
// =====================================================================
__global__ __launch_bounds__(256) void rownorm_kernel(
    const float* __restrict__ qn2r, const float* __restrict__ kn2r,
    float2* __restrict__ qpk, float2* __restrict__ kpk,
    const float* __restrict__ curvp)
{
    int i = blockIdx.x * 256 + threadIdx.x;   // [0, 8192)
    float kv = curv_of(curvp[0]);
    float absk = fabsf(kv);
    float sk = sqrtf(fmaxf(absk, 1e-5f));
    bool euc = (absk < 0.01f);
    float mxn = (1.0f - 1e-3f) / sk;

    float qr = qn2r[i];
    float nq = sqrtf(qr + 1e-12f);
    float sq_ = euc ? 1.f : (kv < 0.f ? fminf(1.f, mxn / nq) : 1.f / (nq * sk));
    qpk[i] = make_float2(qr * sq_ * sq_, sq_);

    float kr = kn2r[i];
    float nk = sqrtf(kr + 1e-12f);
    float sk_ = euc ? 1.f : (kv < 0.f ? fminf(1.f, mxn / nk) : 1.f / (nk * sk));
    kpk[i] = make_float2(kr * sk_ * sk_, sk_);
}

// =====================================================================
// Scores GEMM: 128x128-tile, single-buffer 2-barrier, XCD-swizzled flat
// grid: each XCD owns 8 (bm,b)-strips -> its kbuf panel (<=2MB) + qbuf
// strip (131KB) stay local-L2 across the strip's 16 bn-blocks.
// Epilogue: precomputed {norm^2, scale} float2 loads + dist + exp2 + lsum.
// =====================================================================
__global__ __launch_bounds__(256, 2) void gemm_scores_kernel(
    const u16* __restrict__ qbuf, const u16* __restrict__ kbuf,
    u16* __restrict__ attnH, float* __restrict__ lsum,
    const float2* __restrict__ qpk, const float2* __restrict__ kpk,
    const float* __restrict__ curvp, const float* __restrict__ tempp)
{
    const int lda = 512, ldb = 512, ldc = SEQ;
    // flat grid 1024: xcd = n&7, i = n>>3 in [0,128): bn = i&15,
    // strip = xcd + 8*(i>>4) in [0,64): bm = strip%16, b = strip/16
    int n = blockIdx.x;
    int xcd = n & 7, i = n >> 3;
    int bn = i & 15;
    int strip = xcd + 8 * (i >> 4);
    int bm = strip & 15, b = strip >> 4;
    if (bn > bm) return;   // fully-masked 128x128 tile

    __shared__ __align__(16) u16 As[128 * 64];
    __shared__ __align__(16) u16 Bs[128 * 64];

    int t = threadIdx.x, wave = t >> 6, lane = t & 63;
    int wr = wave >> 1, wc = wave & 1;
    int lrow = lane & 15, quad = lane >> 4;
    int srow = lane >> 3, sc8 = lane & 7;

    const u16* Ab = qbuf + (size_t)(b * SEQ + bm * 128) * lda;
    const u16* Bb = kbuf + (size_t)(b * SEQ + bn * 128) * ldb;

    float4e acc[4][4];
#pragma unroll
    for (int i2 = 0; i2 < 4; i2++)
#pragma unroll
        for (int j = 0; j < 4; j++) acc[i2][j] = (float4e){0.f, 0.f, 0.f, 0.f};

    for (int kt = 0; kt < 8; ++kt) {
        int k0 = kt << 6;
        __syncthreads();
#pragma unroll
        for (int h = 0; h < 4; ++h) {
            int q = wave * 4 + h;
            int row = q * 8 + srow;
            int c = sc8 ^ (row & 7);
            gl_lds16(Ab + (size_t)row * lda + k0 + c * 8, &As[q * 512]);
            gl_lds16(Bb + (size_t)row * ldb + k0 + c * 8, &Bs[q * 512]);
        }
        __syncthreads();
#pragma unroll
        for (int kk = 0; kk < 2; ++kk) {
            short8 af[4], bfr[4];
#pragma unroll
            for (int im = 0; im < 4; im++) {
                int R = wr * 64 + im * 16 + lrow;
                af[im] = *(const short8*)&As[R * 64 + (((kk * 4 + quad) ^ (R & 7)) * 8)];
            }
#pragma unroll
            for (int in = 0; in < 4; in++) {
                int R = wc * 64 + in * 16 + lrow;
                bfr[in] = *(const short8*)&Bs[R * 64 + (((kk * 4 + quad) ^ (R & 7)) * 8)];
            }
#pragma unroll
            for (int im = 0; im < 4; im++)
#pragma unroll
                for (int in = 0; in < 4; in++)
                    acc[im][in] = __builtin_amdgcn_mfma_f32_16x16x32_bf16(af[im], bfr[in], acc[im][in], 0, 0, 0);
        }
    }

    float kv = curv_of(curvp[0]);
    float absk = fabsf(kv);
    float sk = sqrtf(fmaxf(absk, 1e-5f));
    bool euc = (absk < 0.01f);
    float invT = 1.0f / (tempp[0] + 1e-8f);
    float Cexp = -1.4426950408889634f * invT;        // e = exp2(dist * Cexp)
    u16* Cb = attnH + (size_t)b * SEQ * SEQ;

    // per-column {projected norm^2, scale} — pure loads
    float2 kp[4];
#pragma unroll
    for (int in = 0; in < 4; in++)
        kp[in] = kpk[b * SEQ + bn * 128 + wc * 64 + in * 16 + lrow];

    float psum[4][4];
#pragma unroll
    for (int im = 0; im < 4; im++)
#pragma unroll
        for (int r = 0; r < 4; r++) psum[im][r] = 0.f;

#pragma unroll
    for (int im = 0; im < 4; im++) {
#pragma unroll
        for (int r = 0; r < 4; r++) {
            int gi = bm * 128 + wr * 64 + im * 16 + quad * 4 + r;
            float2 qp = qpk[b * SEQ + gi];
            float qn = qp.x;
#pragma unroll
            for (int in = 0; in < 4; in++) {
                int gj = bn * 128 + wc * 64 + in * 16 + lrow;
                float kn = kp[in].x;
                float dot = acc[im][in][r] * qp.y * kp[in].y;
                float diff2 = fmaxf(qn + kn - 2.f * dot, 0.f);
                float dist;
                if (euc) {
                    dist = sqrtf(diff2 + 1e-12f);
                } else if (kv < 0.f) {
                    float denom = fmaxf((1.f - absk * qn) * (1.f - absk * kn), 1e-5f);
                    float arg = fmaxf(1.f + 2.f * absk * diff2 / denom, 1.f + 1e-7f);
                    dist = acoshf(arg) / sk;
                } else {
                    float c = fminf(fmaxf(absk * dot, -1.f + 1e-7f), 1.f - 1e-7f);
                    dist = acosf(c) / sk;
                }
                float e = (gj <= gi) ? exp2f(dist * Cexp) : 0.f;   // scores<=0 -> no max shift
                Cb[(size_t)gi * ldc + gj] = f2bf(e);
                psum[im][r] += e;
            }
        }
    }
#pragma unroll
    for (int im = 0; im < 4; im++)
#pragma unroll
        for (int r = 0; r < 4; r++) {
            float v = psum[im][r];
            v += __shfl_xor(v, 1);
            v += __shfl_xor(v, 2);
            v += __shfl_xor(v, 4);
            v += __shfl_xor(v, 8);
            if (lrow == 0) {
                int gi = bm * 128 + wr * 64 + im * 16 + quad * 4 + r;
                atomicAdd(&lsum[b * SEQ + gi], v);
            }
        }
}

// =====================================================================
// PV GEMM: 64x64, BK=64, single-buffer 2-barrier, full causal K per
// block, XCD-swizzled flat grid: each XCD owns 16 (bm,b)-strips -> its
// vT[b] panel (2MB) + attnH strip stay local-L2 across 8 bn-blocks.
// Direct fp32 store with 1/l + FUSED attnF emission (writer bn==kt%8).
// =====================================================================
__global__ __launch_bounds__(256, 4) void gemm_pv_kernel(
    const u16* __restrict__ attnH, const u16* __restrict__ vT,
    float* __restrict__ out, float* __restrict__ attnF,
    const float* __restrict__ lsum)
{
    const int lda = SEQ, ldb = SEQ, ldc = DIM;
    // flat grid 1024: xcd = n&7, i = n>>3 in [0,128): bn = i&7,
    // strip = xcd + 8*(i>>3) in [0,128): bm = strip%32, b = strip/32
    int n = blockIdx.x;
    int xcd = n & 7, i = n >> 3;
    int bn = i & 7;
    int strip = xcd + 8 * (i >> 3);
    int bm = strip & 31, b = strip >> 5;

    __shared__ __align__(16) u16 As[64 * 64];
    __shared__ __align__(16) u16 Bs[64 * 64];

    int t = threadIdx.x, wave = t >> 6, lane = t & 63;
    int wr = wave >> 1, wc = wave & 1;
    int lrow = lane & 15, quad = lane >> 4;
    int srow = lane >> 3, sc = lane & 7;

    const u16* Ab = attnH + (size_t)b * SEQ * SEQ + (size_t)(bm * 64) * lda;
    const u16* Bb = vT + (size_t)b * DIM * SEQ + (size_t)(bn * 64) * ldb;
    float* attnFb = attnF + (size_t)b * SEQ * SEQ;

    // zero-fill the fully-masked attnF tiles owned by this bn
    {
        int r = t >> 2, c4 = t & 3;
        float4 z = (float4){0.f, 0.f, 0.f, 0.f};
        for (int kt = bm + 1; kt < 32; ++kt)
            if ((kt & 7) == bn) {
                float* dst = attnFb + (size_t)(bm * 64 + r) * SEQ + kt * 64 + c4 * 16;
                ((float4*)dst)[0] = z; ((float4*)dst)[1] = z;
                ((float4*)dst)[2] = z; ((float4*)dst)[3] = z;
            }
    }

    float4e acc[2][2];
#pragma unroll
    for (int i2 = 0; i2 < 2; i2++)
#pragma unroll
        for (int j = 0; j < 2; j++) acc[i2][j] = (float4e){0.f, 0.f, 0.f, 0.f};

    for (int kt = 0; kt <= bm; ++kt) {
        int k0 = kt << 6;
        __syncthreads();
#pragma unroll
        for (int h = 0; h < 2; ++h) {
            int q = wave * 2 + h;
            int row = q * 8 + srow;
            int c = sc ^ (row & 7);
            gl_lds16(Ab + (size_t)row * lda + k0 + c * 8, &As[q * 512]);
            gl_lds16(Bb + (size_t)row * ldb + k0 + c * 8, &Bs[q * 512]);
        }
        __syncthreads();
#pragma unroll
        for (int s = 0; s < 2; ++s) {
            short8 af[2], bfr[2];
#pragma unroll
            for (int im = 0; im < 2; im++) {
                int R = wr * 32 + im * 16 + lrow;
                af[im] = *(const short8*)&As[R * 64 + (((s * 4 + quad) ^ (R & 7)) * 8)];
            }
#pragma unroll
            for (int in = 0; in < 2; in++) {
                int R = wc * 32 + in * 16 + lrow;
                bfr[in] = *(const short8*)&Bs[R * 64 + (((s * 4 + quad) ^ (R & 7)) * 8)];
            }
#pragma unroll
            for (int im = 0; im < 2; im++)
#pragma unroll
                for (int in = 0; in < 2; in++)
                    acc[im][in] = __builtin_amdgcn_mfma_f32_16x16x32_bf16(af[im], bfr[in], acc[im][in], 0, 0, 0);
        }
        // fused attnF emission from the staged LDS A-tile (unique writer: bn == kt%8)
        if ((kt & 7) == bn) {
            int r = t >> 2, c4 = t & 3;
            int gi = bm * 64 + r;
            float invl = 1.0f / lsum[b * SEQ + gi];
            const u16* src = &As[r * 64];
            int j0 = c4 * 2;
            ushort8 u0 = *(const ushort8*)&src[(j0 ^ (r & 7)) * 8];
            ushort8 u1 = *(const ushort8*)&src[((j0 + 1) ^ (r & 7)) * 8];
            float* dst = attnFb + (size_t)gi * SEQ + kt * 64 + c4 * 16;
            float4 f0 = {bf2f(u0[0]) * invl, bf2f(u0[1]) * invl, bf2f(u0[2]) * invl, bf2f(u0[3]) * invl};
            float4 f1 = {bf2f(u0[4]) * invl, bf2f(u0[5]) * invl, bf2f(u0[6]) * invl, bf2f(u0[7]) * invl};
            float4 f2 = {bf2f(u1[0]) * invl, bf2f(u1[1]) * invl, bf2f(u1[2]) * invl, bf2f(u1[3]) * invl};
            float4 f3 = {bf2f(u1[4]) * invl, bf2f(u1[5]) * invl, bf2f(u1[6]) * invl, bf2f(u1[7]) * invl};
            ((float4*)dst)[0] = f0; ((float4*)dst)[1] = f1;
            ((float4*)dst)[2] = f2; ((float4*)dst)[3] = f3;
        }
    }

    float* Cb = out + (size_t)b * SEQ * DIM;
#pragma unroll
    for (int im = 0; im < 2; im++)
#pragma unroll
        for (int r = 0; r < 4; r++) {
            int gi = bm * 64 + wr * 32 + im * 16 + quad * 4 + r;
            float invl = 1.0f / lsum[b * SEQ + gi];
#pragma unroll
            for (int in = 0; in < 2; in++) {
                int gd = bn * 64 + wc * 32 + in * 16 + lrow;
                Cb[(size_t)gi * ldc + gd] = acc[im][in][r] * invl;
            }
        }
}

// ---------------- launch ----------------
extern "C" void kernel_launch(void* const* d_in, const int* in_sizes, int n_in,
                              void* d_out, int out_size, void* d_ws, size_t ws_size,
                              hipStream_t stream) {
    (void)in_sizes; (void)n_in; (void)out_size; (void)ws_size;

    const float* x    = (const float*)d_in[0];
    const float* Wq   = (const float*)d_in[1];
    const float* bq   = (const float*)d_in[2];
    const float* Wk   = (const float*)d_in[3];
    const float* bk   = (const float*)d_in[4];
    const float* Wv   = (const float*)d_in[5];
    const float* bv   = (const float*)d_in[6];
    const float* curv = (const float*)d_in[7];
    const float* temp = (const float*)d_in[8];

    float* out   = (float*)d_out;                       // [4][2048][512]
    float* attnF = out + (size_t)NB * SEQ * DIM;        // [4][2048][2048]

    char* ws = (char*)d_ws;
    // layout (bytes), peak 58.95 MB:
    //   0        attnH  33,554,432  (aliases x_bf@0 (8.4M) + Wcat@8388608
    //                                (1.5M) — both dead after QKV)
    //   33554432 qbuf    8,388,608  [8192][512] bf16
    //   41943040 kbuf    8,388,608  [8192][512] bf16
    //   50331648 vT      8,388,608  [4][512][2048] bf16
    //   58720256 qn2r       32,768  raw row-norm sums (f32)
    //   58753024 kn2r       32,768
    //   58785792 lsum       32,768
    //   58818560 qpk        65,536  float2 {proj norm^2, scale}
    //   58884096 kpk        65,536
    u16*   x_bf  = (u16*)(ws + 0);
    u16*   Wcat  = (u16*)(ws + 8388608);
    u16*   attnH = (u16*)(ws + 0);
    u16*   qbuf  = (u16*)(ws + 33554432);
    u16*   kbuf  = (u16*)(ws + 41943040);
    u16*   vT    = (u16*)(ws + 50331648);
    float* qn2r  = (float*)(ws + 58720256);
    float* kn2r  = (float*)(ws + 58753024);
    float* lsum  = (float*)(ws + 58785792);
    float2* qpk  = (float2*)(ws + 58818560);
    float2* kpk  = (float2*)(ws + 58884096);

    // K0: conversions + zero lsum/qn2r/kn2r
    {
        int n_tot = (NB * SEQ * DIM + 3 * DIM * DIM) / 4;
        cvt_all_kernel<<<(n_tot + 255) / 256, 256, 0, stream>>>(
            x, Wq, Wk, Wv, x_bf, Wcat, lsum, qn2r, kn2r);
    }

    // K1: QKV GEMM (M=8192, N=1536, K=512), XCD-swizzled flat grid 768
    gemm_qkv_kernel<<<768, 256, 0, stream>>>(
        x_bf, Wcat, qbuf, kbuf, vT, bq, bk, bv, qn2r, kn2r);

    // K1.5: per-row projection scales
    rownorm_kernel<<<NB * SEQ / 256, 256, 0, stream>>>(qn2r, kn2r, qpk, kpk, curv);

    // K2: scores + dist + exp + row sums, XCD-swizzled flat grid 1024
    gemm_scores_kernel<<<1024, 256, 0, stream>>>(
        qbuf, kbuf, attnH, lsum, qpk, kpk, curv, temp);

    // K3: PV + fused attnF, XCD-swizzled flat grid 1024
    gemm_pv_kernel<<<1024, 256, 0, stream>>>(
        attnH, vT, out, attnF, lsum);
}